// Round 4
// baseline (195.486 us; speedup 1.0000x reference)
//
#include <hip/hip_runtime.h>

// DWT2d db4, single fused kernel — row pass reads global directly (no sm_x),
// LDS only holds row-pass lo/hi (19.5 KB) -> 8 blocks/CU occupancy.
// x: (96, 512, 512) fp32 -> out: (96*4, 256, 256) fp32
// out[bc*4+s][i][j] = sum_{p,q} x[bc][(2i+p)%512][(2j+q)%512] * fH[s][p]*fW[s][q]

#define TI 16               // output rows per block
#define TJ 64               // output cols per block
#define PR (2*TI + 6)       // 38 intermediate rows
#define HH 512
#define WW 512

typedef float v4f __attribute__((ext_vector_type(4)));

__global__ __launch_bounds__(256, 8)
void dwt2d_db4_kernel(const float* __restrict__ x,
                      const float* __restrict__ dec,
                      float* __restrict__ out) {
    __shared__ __align__(16) float sm_lo[PR][TJ];   // 9728 B
    __shared__ __align__(16) float sm_hi[PR][TJ];   // 9728 B

    const int tid = threadIdx.x;
    const int jt  = blockIdx.x;        // 0..3
    const int it  = blockIdx.y;        // 0..15
    const int bc  = blockIdx.z;        // 0..95

    const int rowBase = it * (2 * TI);
    const int colBase = jt * (2 * TJ);

    float flo[8], fhi[8];
#pragma unroll
    for (int k = 0; k < 8; ++k) { flo[k] = dec[k]; fhi[k] = dec[8 + k]; }

    const float* xb = x + (size_t)bc * HH * WW;

    // ---- Phase A: row pass straight from global. Thread -> output pair (2t,2t+1)
    //      of intermediate row r: 3 coalesced dwordx4 loads (overlap hits L1). ----
    for (int task = tid; task < PR * (TJ / 2); task += 256) {   // 1216 tasks
        int r = task >> 5;            // / 32
        int t = task & 31;
        int gr = rowBase + r; if (gr >= HH) gr -= HH;
        const float* src = xb + gr * WW;
        int gc = colBase + 4 * t;

        float w[12];
        if (gc + 11 < WW) {
            float4 v0 = *(const float4*)(src + gc);
            float4 v1 = *(const float4*)(src + gc + 4);
            float4 v2 = *(const float4*)(src + gc + 8);
            w[0]=v0.x; w[1]=v0.y; w[2]=v0.z;  w[3]=v0.w;
            w[4]=v1.x; w[5]=v1.y; w[6]=v1.z;  w[7]=v1.w;
            w[8]=v2.x; w[9]=v2.y; w[10]=v2.z; w[11]=v2.w;
        } else {                      // circular wrap: only jt==3, t==31
#pragma unroll
            for (int k = 0; k < 12; ++k) w[k] = src[(gc + k) & (WW - 1)];
        }

        float lo0 = 0.f, hi0 = 0.f, lo1 = 0.f, hi1 = 0.f;
#pragma unroll
        for (int q = 0; q < 8; ++q) {
            lo0 += w[q]     * flo[q];
            hi0 += w[q]     * fhi[q];
            lo1 += w[q + 2] * flo[q];
            hi1 += w[q + 2] * fhi[q];
        }
        *(float2*)&sm_lo[r][2 * t] = make_float2(lo0, lo1);
        *(float2*)&sm_hi[r][2 * t] = make_float2(hi0, hi1);
    }
    __syncthreads();

    // ---- Phase B: col pass. Thread -> 4 consecutive j, all 4 subbands.
    //      16x b128 LDS reads, nontemporal coalesced dwordx4 stores. ----
    {
        int i  = tid >> 4;            // 0..15
        int jb = tid & 15;            // 0..15
        int j0 = 4 * jb;
        float llx=0.f, lly=0.f, llz=0.f, llw=0.f;
        float lhx=0.f, lhy=0.f, lhz=0.f, lhw=0.f;
        float hlx=0.f, hly=0.f, hlz=0.f, hlw=0.f;
        float hhx=0.f, hhy=0.f, hhz=0.f, hhw=0.f;
#pragma unroll
        for (int p = 0; p < 8; ++p) {
            float4 a = *(const float4*)&sm_lo[2 * i + p][j0];
            float4 b = *(const float4*)&sm_hi[2 * i + p][j0];
            float cl = flo[p], ch = fhi[p];
            llx += a.x * cl; lly += a.y * cl; llz += a.z * cl; llw += a.w * cl;
            lhx += a.x * ch; lhy += a.y * ch; lhz += a.z * ch; lhw += a.w * ch;
            hlx += b.x * cl; hly += b.y * cl; hlz += b.z * cl; hlw += b.w * cl;
            hhx += b.x * ch; hhy += b.y * ch; hhz += b.z * ch; hhw += b.w * ch;
        }
        int oi = it * TI + i;
        int oj = jt * TJ + j0;
        size_t base = ((size_t)(bc * 4) * 256 + oi) * 256 + oj;
        v4f ll = { llx, lly, llz, llw };
        v4f lh = { lhx, lhy, lhz, lhw };
        v4f hl = { hlx, hly, hlz, hlw };
        v4f hh = { hhx, hhy, hhz, hhw };
        __builtin_nontemporal_store(ll, (v4f*)&out[base]);
        __builtin_nontemporal_store(lh, (v4f*)&out[base + 1 * 65536]);
        __builtin_nontemporal_store(hl, (v4f*)&out[base + 2 * 65536]);
        __builtin_nontemporal_store(hh, (v4f*)&out[base + 3 * 65536]);
    }
}

extern "C" void kernel_launch(void* const* d_in, const int* in_sizes, int n_in,
                              void* d_out, int out_size, void* d_ws, size_t ws_size,
                              hipStream_t stream) {
    const float* x   = (const float*)d_in[0];
    const float* dec = (const float*)d_in[1];
    float* out = (float*)d_out;

    dim3 grid(256 / TJ, 256 / TI, 96);   // (4, 16, 96)
    dim3 block(256);
    dwt2d_db4_kernel<<<grid, block, 0, stream>>>(x, dec, out);
}

// Round 5
// 172.953 us; speedup vs baseline: 1.1303x; 1.1303x over previous
//
#include <hip/hip_runtime.h>

// DWT2d db4 — async global_load_lds staging + small tile for occupancy.
// x: (96, 512, 512) fp32 -> out: (96*4, 256, 256) fp32
// out[bc*4+s][i][j] = sum_{p,q} x[bc][(2i+p)%512][(2j+q)%512] * fH[s][p]*fW[s][q]

#define TI 8                // output rows per block
#define TJ 64               // output cols per block
#define PR (2*TI + 6)       // 22 patch rows
#define PC 136              // padded patch cols (need 134), 34 float4 granules/row
#define NG ((PR * PC) / 4)  // 748 float4 granules in patch
#define HH 512
#define WW 512

typedef float v2f __attribute__((ext_vector_type(2)));
typedef const __attribute__((address_space(1))) void gas_t;   // global
typedef __attribute__((address_space(3))) void las_t;         // LDS

__global__ __launch_bounds__(256)
void dwt2d_db4_kernel(const float* __restrict__ x,
                      const float* __restrict__ dec,
                      float* __restrict__ out) {
    __shared__ __align__(16) float sm_x[PR * PC];   // 11968 B (flat: DMA-ordered)
    __shared__ __align__(16) float sm_lo[PR][TJ];   //  5632 B
    __shared__ __align__(16) float sm_hi[PR][TJ];   //  5632 B  -> total 23232 B

    const int tid  = threadIdx.x;
    const int wid  = tid >> 6;
    const int jt   = blockIdx.x;       // 0..3
    const int it   = blockIdx.y;       // 0..31
    const int bc   = blockIdx.z;       // 0..95

    const int rowBase = it * (2 * TI);
    const int colBase = jt * (2 * TJ);

    float flo[8], fhi[8];
#pragma unroll
    for (int k = 0; k < 8; ++k) { flo[k] = dec[k]; fhi[k] = dec[8 + k]; }

    const float* xb = x + (size_t)bc * HH * WW;

    // ---- Phase A: async DMA patch -> LDS. 3 wave-batches of 16B granules,
    //      fire-and-forget; single drain at the barrier. ----
#pragma unroll
    for (int k = 0; k < 3; ++k) {
        int g = k * 256 + tid;                     // flat float4 granule index
        // wave-uniform LDS dest: hw adds lane*16
        las_t* lp = (las_t*)((char*)sm_x + k * 4096 + wid * 1024);
        if (g < NG) {
            int r  = g / 34;
            int c4 = g - r * 34;
            int gr = rowBase + r;  if (gr >= HH) gr -= HH;
            int gc = colBase + 4 * c4; if (gc >= WW) gc -= WW;   // 16B-aligned, no row cross
            const float* gp = xb + gr * WW + gc;
            __builtin_amdgcn_global_load_lds((gas_t*)gp, lp, 16, 0, 0);
        }
    }
    __syncthreads();

    // ---- Phase B: row pass. Thread -> output pair (2t,2t+1) of patch row r.
    //      3x ds_read_b128 (lane-consecutive), float2 LDS writes. ----
    for (int task = tid; task < PR * (TJ / 2); task += 256) {   // 704 tasks
        int r = task >> 5;
        int t = task & 31;
        const float* xr = &sm_x[r * PC + 4 * t];
        float4 v0 = *(const float4*)(xr);
        float4 v1 = *(const float4*)(xr + 4);
        float4 v2 = *(const float4*)(xr + 8);
        float w[12] = { v0.x, v0.y, v0.z, v0.w,
                        v1.x, v1.y, v1.z, v1.w,
                        v2.x, v2.y, v2.z, v2.w };
        float lo0 = 0.f, hi0 = 0.f, lo1 = 0.f, hi1 = 0.f;
#pragma unroll
        for (int q = 0; q < 8; ++q) {
            lo0 += w[q]     * flo[q];
            hi0 += w[q]     * fhi[q];
            lo1 += w[q + 2] * flo[q];
            hi1 += w[q + 2] * fhi[q];
        }
        *(float2*)&sm_lo[r][2 * t] = make_float2(lo0, lo1);
        *(float2*)&sm_hi[r][2 * t] = make_float2(hi0, hi1);
    }
    __syncthreads();

    // ---- Phase C: col pass. Thread -> 2 consecutive j, all 4 subbands.
    //      16x ds_read_b64 (contiguous per half-wave), nontemporal dwordx2 stores. ----
    {
        int i  = tid >> 5;            // 0..7
        int j0 = (tid & 31) * 2;      // 0..62
        float ll0=0.f, ll1=0.f, lh0=0.f, lh1=0.f;
        float hl0=0.f, hl1=0.f, hh0=0.f, hh1=0.f;
#pragma unroll
        for (int p = 0; p < 8; ++p) {
            float2 a = *(const float2*)&sm_lo[2 * i + p][j0];
            float2 b = *(const float2*)&sm_hi[2 * i + p][j0];
            float cl = flo[p], ch = fhi[p];
            ll0 += a.x * cl; ll1 += a.y * cl;
            lh0 += a.x * ch; lh1 += a.y * ch;
            hl0 += b.x * cl; hl1 += b.y * cl;
            hh0 += b.x * ch; hh1 += b.y * ch;
        }
        int oi = it * TI + i;
        int oj = jt * TJ + j0;
        size_t base = ((size_t)(bc * 4) * 256 + oi) * 256 + oj;
        v2f ll = { ll0, ll1 }, lh = { lh0, lh1 };
        v2f hl = { hl0, hl1 }, hh = { hh0, hh1 };
        __builtin_nontemporal_store(ll, (v2f*)&out[base]);
        __builtin_nontemporal_store(lh, (v2f*)&out[base + 1 * 65536]);
        __builtin_nontemporal_store(hl, (v2f*)&out[base + 2 * 65536]);
        __builtin_nontemporal_store(hh, (v2f*)&out[base + 3 * 65536]);
    }
}

extern "C" void kernel_launch(void* const* d_in, const int* in_sizes, int n_in,
                              void* d_out, int out_size, void* d_ws, size_t ws_size,
                              hipStream_t stream) {
    const float* x   = (const float*)d_in[0];
    const float* dec = (const float*)d_in[1];
    float* out = (float*)d_out;

    dim3 grid(256 / TJ, 256 / TI, 96);   // (4, 32, 96)
    dim3 block(256);
    dwt2d_db4_kernel<<<grid, block, 0, stream>>>(x, dec, out);
}